// Round 8
// baseline (371.619 us; speedup 1.0000x reference)
//
#include <hip/hip_runtime.h>
#include <hip/hip_cooperative_groups.h>
#include <hip/hip_bf16.h>
#include <stdint.h>

namespace cg = cooperative_groups;

#define B_ 4
#define T_ 8192
#define D_ 512
#define H_ 512
#define M_ (B_ * T_)          // 32768 rows
#define SEG 32                // scan segment length (t steps)
#define SPB 256               // segments per batch chain (T_/SEG)
#define NSEG (M_ / SEG)       // 1024 segments total
#define NTILE 2048            // gemm tiles (M/128 * H/64)

typedef __attribute__((ext_vector_type(8))) short short8;
typedef __attribute__((ext_vector_type(4))) float floatx4;
typedef __attribute__((ext_vector_type(2))) float float2e;

__device__ __forceinline__ unsigned short f2bf(float f) {
    union { float f; unsigned int u; } v; v.f = f;
    unsigned int u = v.u;
    u += 0x7fffu + ((u >> 16) & 1u);   // RNE
    return (unsigned short)(u >> 16);
}
__device__ __forceinline__ float bf_lo(unsigned int u) {
    union { unsigned int i; float f; } a; a.i = u << 16; return a.f;
}
__device__ __forceinline__ float bf_hi(unsigned int u) {
    union { unsigned int i; float f; } a; a.i = u & 0xffff0000u; return a.f;
}
__device__ __forceinline__ unsigned int pk_cd(float c, float d) {
    return (unsigned int)f2bf(c) | ((unsigned int)f2bf(d) << 16);
}

// ---------------------------------------------------------------------------
// fused f32 -> bf16 converter: grid-stride streaming (2048 blocks).
// ---------------------------------------------------------------------------
#define X8 (M_ * D_ / 8)
#define W8 (H_ * D_ / 8)

__global__ __launch_bounds__(256)
void conv_all(const float* __restrict__ x,
              const float* __restrict__ Wz,
              const float* __restrict__ Wh,
              unsigned short* __restrict__ xbf,
              unsigned short* __restrict__ Wf)
{
    const int gid    = blockIdx.x * blockDim.x + threadIdx.x;
    const int stride = gridDim.x * blockDim.x;
    for (int i = gid; i < X8; i += stride) {
        floatx4 a = __builtin_nontemporal_load((const floatx4*)x + 2 * i);
        floatx4 b = __builtin_nontemporal_load((const floatx4*)x + 2 * i + 1);
        short8 w;
        w[0] = (short)f2bf(a[0]); w[1] = (short)f2bf(a[1]);
        w[2] = (short)f2bf(a[2]); w[3] = (short)f2bf(a[3]);
        w[4] = (short)f2bf(b[0]); w[5] = (short)f2bf(b[1]);
        w[6] = (short)f2bf(b[2]); w[7] = (short)f2bf(b[3]);
        *((short8*)xbf + i) = w;
    }
    if (gid < 2 * W8) {
        const int i = gid;
        const float* src = (i < W8) ? Wz : Wh;
        const int idx = (i < W8) ? i : i - W8;
        floatx4 a = __builtin_nontemporal_load((const floatx4*)src + 2 * idx);
        floatx4 b = __builtin_nontemporal_load((const floatx4*)src + 2 * idx + 1);
        short8 w;
        w[0] = (short)f2bf(a[0]); w[1] = (short)f2bf(a[1]);
        w[2] = (short)f2bf(a[2]); w[3] = (short)f2bf(a[3]);
        w[4] = (short)f2bf(b[0]); w[5] = (short)f2bf(b[1]);
        w[6] = (short)f2bf(b[2]); w[7] = (short)f2bf(b[3]);
        *((short8*)Wf + i) = w;
    }
}

// ---------------------------------------------------------------------------
// ONE cooperative kernel, GRID-STRIDE phases (any co-resident grid size):
// phase 1: gemm tiles blk in [0,2048) stride gridDim
// phase 2: chain-blocks cb in [0,512), 4 chains each (wave-per-chain)
// phase 3: segments sg in [0,1024)
// Launched with grid = occupancy-guaranteed co-resident block count.
// ---------------------------------------------------------------------------
#define LDSB 32768     // union: 2x16 KB staging bufs | 128x64 dword cd tile

__global__ __launch_bounds__(256, 4)
void fused_gsa(const unsigned short* __restrict__ xbf,
               const unsigned short* __restrict__ Wf,   // [0:512)=Wz, [512:1024)=Wh
               const float* __restrict__ bz, const float* __restrict__ bh,
               const float* __restrict__ h_prev,
               unsigned int* __restrict__ cd,           // [M][512] (c,d) bf16-pair dwords
               float2* __restrict__ Sagg,               // [2048 chains][256 segs]
               float* __restrict__ Hseg,                // [2048 chains][256 segs]
               float* __restrict__ out)
{
    cg::grid_group grid = cg::this_grid();
    __shared__ __align__(16) char smem[LDSB];
    unsigned short* lds = (unsigned short*)smem;      // staging (shorts)
    unsigned int*   cdl = (unsigned int*)smem;        // cd tile (dwords), XOR-swizzled

    const int tid  = threadIdx.x;
    const int lane = tid & 63;
    const int wave = tid >> 6;
    const int l15  = lane & 15;
    const int quad = lane >> 4;
    const int srow = lane >> 2;
    const int sp   = lane & 3;
    const int wm = (wave >> 1) * 64;
    const int wn = (wave & 1) * 32;

    // ------------------ phase 1: dual GEMM, grid-stride over 2048 tiles --------
    #pragma unroll 1
    for (int blk = blockIdx.x; blk < NTILE; blk += gridDim.x) {
        const int xcd  = blk & 7;
        const int nblk = (blk >> 3) & 7;
        const int mblk = xcd * 32 + (blk >> 6);
        const int m0 = mblk * 128;
        const int n0 = nblk * 64;

        #define STAGE(p, kt)                                                          \
        {                                                                             \
            const int kb = (kt) * 32;                                                 \
            unsigned short* bb = lds + (p) * 8192;                                    \
            _Pragma("unroll")                                                         \
            for (int r = 0; r < 2; ++r) {                                             \
                const int chunk = r * 4 + wave;                                       \
                const int row   = chunk * 16 + srow;                                  \
                const int kp    = sp ^ (row & 3);                                     \
                __builtin_amdgcn_global_load_lds(                                     \
                    (const __attribute__((address_space(1))) unsigned int*)           \
                        (xbf + (size_t)(m0 + row) * D_ + kb + kp * 8),                \
                    (__attribute__((address_space(3))) unsigned int*)(bb + chunk * 512),\
                    16, 0, 0);                                                        \
            }                                                                         \
            {                                                                         \
                const int row = wave * 16 + srow;                                     \
                const int kp  = sp ^ (row & 3);                                       \
                __builtin_amdgcn_global_load_lds(                                     \
                    (const __attribute__((address_space(1))) unsigned int*)           \
                        (Wf + (size_t)(n0 + row) * D_ + kb + kp * 8),                 \
                    (__attribute__((address_space(3))) unsigned int*)(bb + 4096 + wave * 512),\
                    16, 0, 0);                                                        \
                __builtin_amdgcn_global_load_lds(                                     \
                    (const __attribute__((address_space(1))) unsigned int*)           \
                        (Wf + (size_t)(512 + n0 + row) * D_ + kb + kp * 8),           \
                    (__attribute__((address_space(3))) unsigned int*)(bb + 6144 + wave * 512),\
                    16, 0, 0);                                                        \
            }                                                                         \
        }

        floatx4 acc_z[4][2], acc_h[4][2];
        #pragma unroll
        for (int i = 0; i < 4; ++i)
            #pragma unroll
            for (int j = 0; j < 2; ++j) { acc_z[i][j] = (floatx4)0.0f; acc_h[i][j] = (floatx4)0.0f; }

        STAGE(0, 0);

        for (int kt = 0; kt < 16; ++kt) {
            __syncthreads();
            const int base = (kt & 1) * 8192;
            short8 af[4], zf[2], hf[2];
            #pragma unroll
            for (int i = 0; i < 4; ++i) {
                const int ra = wm + i * 16 + l15;
                af[i] = *(const short8*)&lds[base + ra * 32 + ((quad ^ (ra & 3)) * 8)];
            }
            #pragma unroll
            for (int j = 0; j < 2; ++j) {
                const int rb = wn + j * 16 + l15;
                zf[j] = *(const short8*)&lds[base + 4096 + rb * 32 + ((quad ^ (rb & 3)) * 8)];
                hf[j] = *(const short8*)&lds[base + 6144 + rb * 32 + ((quad ^ (rb & 3)) * 8)];
            }
            if (kt < 15) STAGE((kt + 1) & 1, kt + 1);
            #pragma unroll
            for (int i = 0; i < 4; ++i)
                #pragma unroll
                for (int j = 0; j < 2; ++j) {
                    acc_z[i][j] = __builtin_amdgcn_mfma_f32_16x16x32_bf16(zf[j], af[i], acc_z[i][j], 0, 0, 0);
                    acc_h[i][j] = __builtin_amdgcn_mfma_f32_16x16x32_bf16(hf[j], af[i], acc_h[i][j], 0, 0, 0);
                }
        }

        __syncthreads();   // staging LDS dead; reuse as cd tile

        #pragma unroll
        for (int j = 0; j < 2; ++j) {
            const int hlb = wn + j * 16 + quad * 4;
            const float4 bzv = *(const float4*)&bz[n0 + hlb];
            const float4 bhv = *(const float4*)&bh[n0 + hlb];
            #pragma unroll
            for (int i = 0; i < 4; ++i) {
                const int mloc = wm + i * 16 + l15;
                uint4 w;
                #pragma unroll
                for (int r = 0; r < 4; ++r) {
                    float kz = acc_z[i][j][r] + ((const float*)&bzv)[r];
                    float hp = acc_h[i][j][r] + ((const float*)&bhv)[r];
                    float c  = 1.0f / (1.0f + __expf(kz));   // sigmoid(-kz)
                    float g  = (hp >= 0.0f) ? (hp + 0.5f) : (1.0f / (1.0f + __expf(-hp)));
                    float d  = (1.0f - c) * g;
                    ((unsigned int*)&w)[r] = pk_cd(c, d);
                }
                *(uint4*)&cd[(size_t)(m0 + mloc) * H_ + n0 + hlb] = w;
                // XOR swizzle: col' = hlb ^ ((row&7)<<2); bijective per row
                *(uint4*)&cdl[mloc * 64 + (hlb ^ ((mloc & 7) << 2))] = w;
            }
        }

        __syncthreads();

        // segment scans: wave = 32-t segment, lane = h column; chain-major
        {
            float C = 1.0f, Dv = 0.0f;
            const int t0 = wave * 32;
            #pragma unroll
            for (int t = 0; t < 32; ++t) {
                const int row = t0 + t;
                unsigned int u = cdl[row * 64 + (lane ^ ((row & 7) << 2))];
                float c = bf_lo(u), d = bf_hi(u);
                Dv = fmaf(c, Dv, d);
                C *= c;
            }
            const int chain = (m0 >> 13) * 512 + n0 + lane;      // b*512 + h
            const int seg   = ((m0 >> 5) & 255) + wave;          // in-batch segment
            Sagg[(size_t)chain * SPB + seg] = make_float2(C, Dv);
        }
        __syncthreads();   // protect cdl reads before next tile's STAGE
        #undef STAGE
    }

    grid.sync();

    // ------------------ phase 2: inter-segment scan, 4 chains per block-iter ---
    #pragma unroll 1
    for (int cb = blockIdx.x; cb < 512; cb += gridDim.x) {
        const int chain = cb * 4 + wave;
        const float2* spp = Sagg + (size_t)chain * SPB + lane * 4;
        float4 q0 = *(const float4*)&spp[0];   // (C0,D0,C1,D1)
        float4 q1 = *(const float4*)&spp[2];   // (C2,D2,C3,D3)
        float C = q0.x, D = q0.y;
        D = fmaf(q0.z, D, q0.w);  C *= q0.z;
        D = fmaf(q1.x, D, q1.y);  C *= q1.x;
        D = fmaf(q1.z, D, q1.w);  C *= q1.z;
        #pragma unroll
        for (int off = 1; off < 64; off <<= 1) {
            float Cp = __shfl_up(C, off, 64);
            float Dp = __shfl_up(D, off, 64);
            if (lane >= off) { D = fmaf(C, Dp, D); C *= Cp; }
        }
        float Ce = __shfl_up(C, 1, 64);
        float De = __shfl_up(D, 1, 64);
        if (lane == 0) { Ce = 1.0f; De = 0.0f; }
        const float h0 = h_prev[chain];
        float hs = fmaf(Ce, h0, De);
        float4 o;
        o.x = hs;
        hs = fmaf(q0.x, hs, q0.y); o.y = hs;
        hs = fmaf(q0.z, hs, q0.w); o.z = hs;
        hs = fmaf(q1.x, hs, q1.y); o.w = hs;
        *(float4*)&Hseg[(size_t)chain * SPB + lane * 4] = o;
    }

    grid.sync();

    // ------------------ phase 3: apply, grid-stride over 1024 segments ---------
    #pragma unroll 1
    for (int sg = blockIdx.x; sg < NSEG; sg += gridDim.x) {
        const int b  = sg >> 8;
        const int s  = sg & 255;
        const int h  = tid * 2;
        float hs0 = Hseg[(size_t)(b * 512 + h)     * SPB + s];
        float hs1 = Hseg[(size_t)(b * 512 + h + 1) * SPB + s];
        const unsigned int* base = cd + (size_t)sg * SEG * H_ + h;
        float* ob = out + (size_t)sg * SEG * H_ + h;
        #pragma unroll
        for (int t = 0; t < SEG; ++t) {
            uint2 v = *(const uint2*)(base + (size_t)t * H_);
            hs0 = fmaf(bf_lo(v.x), hs0, bf_hi(v.x));
            hs1 = fmaf(bf_lo(v.y), hs1, bf_hi(v.y));
            float2e o; o.x = hs0; o.y = hs1;
            __builtin_nontemporal_store(o, (float2e*)(ob + (size_t)t * H_));
        }
    }
}

// ---------------------------------------------------------------------------
extern "C" void kernel_launch(void* const* d_in, const int* in_sizes, int n_in,
                              void* d_out, int out_size, void* d_ws, size_t ws_size,
                              hipStream_t stream)
{
    const float* x      = (const float*)d_in[0];
    const float* h_prev = (const float*)d_in[1];
    const float* W_h    = (const float*)d_in[2];
    const float* b_h    = (const float*)d_in[3];
    const float* W_z    = (const float*)d_in[4];
    const float* b_z    = (const float*)d_in[5];
    float* out = (float*)d_out;

    // xbf lives in d_out (dead until apply phase overwrites all of it)
    unsigned short* xbf = (unsigned short*)d_out;

    char* ws = (char*)d_ws;
    unsigned int* cd = (unsigned int*)ws;                       // 67.1 MB
    size_t cd_bytes = (size_t)M_ * H_ * 4;
    unsigned short* Wf = (unsigned short*)(ws + cd_bytes);      // 1 MB
    size_t wf_bytes = (size_t)2 * H_ * D_ * sizeof(unsigned short);
    float2* Sagg = (float2*)(ws + cd_bytes + wf_bytes);         // 4 MB
    float*  Hseg = (float*)((char*)Sagg + (size_t)2048 * SPB * sizeof(float2)); // 2 MB

    // 0) convert inputs to bf16 (grid-stride streaming)
    conv_all<<<dim3(2048), dim3(256), 0, stream>>>(x, W_z, W_h, xbf, Wf);

    // 1) gemm + interseg + apply in ONE cooperative kernel, sized to the
    //    occupancy-guaranteed co-resident block count (r7 failed silently:
    //    1024 blocks exceeded co-residency and the launch was rejected).
    int bpc = 0;
    (void)hipOccupancyMaxActiveBlocksPerMultiprocessor(&bpc, (const void*)fused_gsa,
                                                       256, 0);
    if (bpc < 1) bpc = 1;
    int grid = bpc * 256;              // 256 CUs on MI355X
    if (grid > 1024) grid = 1024;      // never need more than 1 block/segment
    if (grid < 256)  grid = 256;

    const unsigned short* xbf_c = xbf;
    const unsigned short* Wf_c  = Wf;
    const float* bz_c = b_z;
    const float* bh_c = b_h;
    const float* hp_c = h_prev;
    unsigned int* cd_c = cd;
    float2* Sagg_c = Sagg;
    float* Hseg_c = Hseg;
    float* out_c = out;
    void* args[] = { (void*)&xbf_c, (void*)&Wf_c, (void*)&bz_c, (void*)&bh_c,
                     (void*)&hp_c, (void*)&cd_c, (void*)&Sagg_c, (void*)&Hseg_c,
                     (void*)&out_c };
    hipLaunchCooperativeKernel((void*)fused_gsa, dim3(grid), dim3(256),
                               args, 0, stream);
}